// Round 1
// baseline (215.506 us; speedup 1.0000x reference)
//
#include <hip/hip_runtime.h>

// CommNet forward, fp32, model-id-routed linears.
// B=512 examples, M=32 models, H=256, NAG=8, NACT=16.
// Strategy: group examples by model id (avg ~16/model), then batched
// per-model GEMMs so each weight is streamed from HBM ~once (memory-bound,
// ~90MB total -> ~14us floor at 6.3 TB/s).

constexpr int Bn = 512, Mn = 32, NAGn = 8, Hn = 256, NACTn = 16;
constexpr int On = Hn * NAGn;   // 2048
constexpr int HP = Hn + 4;      // LDS row pad: breaks 4-way bank conflict on x-broadcast reads

// ---------------- kernel 1: group examples by model id ----------------
__global__ __launch_bounds__(512) void k_group(const int* __restrict__ ids,
                                               int* __restrict__ ofs,
                                               int* __restrict__ list) {
  __shared__ int cnt[Mn];
  __shared__ int basep[Mn];
  int t = threadIdx.x;            // t = example index (512 threads)
  if (t < Mn) cnt[t] = 0;
  __syncthreads();
  int m = ids[t];
  int pos = atomicAdd(&cnt[m], 1);
  __syncthreads();
  if (t == 0) {
    int s = 0;
    for (int i = 0; i < Mn; i++) { basep[i] = s; s += cnt[i]; }
  }
  __syncthreads();
  if (t <= Mn) ofs[t] = (t == Mn) ? Bn : basep[t];
  list[basep[m] + pos] = t;
}

// ---------------- kernel 2: hidstate = tanh(enc + x_c@Wc + bc + x_r@Wr + br) --
// block = 256 threads = 16 example-rows x 16 col4-groups (covers 16 ex, 64 cols)
// grid  = (32 models, 4 col-tiles, 4 chunks); strided tail loop handles any count.
__global__ __launch_bounds__(256) void k_hid(
    const float* __restrict__ comm_in, const int* __restrict__ inp,
    const float* __restrict__ prev_hid,
    const float* __restrict__ Wc, const float* __restrict__ bc,
    const float* __restrict__ Wr, const float* __restrict__ br,
    const float* __restrict__ lut, const float* __restrict__ enc_bias,
    const int* __restrict__ ofs, const int* __restrict__ list,
    float* __restrict__ hid_out) {
  constexpr int E = 16;
  int m = blockIdx.x;
  int ct = blockIdx.y;
  int ch = blockIdx.z;
  int beg = ofs[m], end = ofs[m + 1];
  if (beg + ch * E >= end) return;

  __shared__ float cs[E][HP];   // summed comm_in rows
  __shared__ float ph[E][HP];   // prev_hid rows
  __shared__ int eidx[E];

  int tid = threadIdx.x;
  int col4 = tid & 15;
  int erow = tid >> 4;
  int col = ct * 64 + col4 * 4;

  const float* wcp = Wc + (size_t)m * Hn * Hn + col;
  const float* wrp = Wr + (size_t)m * Hn * Hn + col;

  for (int base0 = beg + ch * E; base0 < end; base0 += 4 * E) {
    int ne = min(E, end - base0);
    if (tid < E) eidx[tid] = list[base0 + min(tid, ne - 1)];
    __syncthreads();
    // stage: agent-summed comm_in and prev_hid for the chunk (coalesced)
    for (int j = 0; j < E; j++) {
      int e = eidx[j];
      const float* cip = comm_in + (size_t)e * NAGn * Hn + tid;
      float s = 0.f;
#pragma unroll
      for (int a = 0; a < NAGn; a++) s += cip[a * Hn];
      cs[j][tid] = s;
      ph[j][tid] = prev_hid[e * Hn + tid];
    }
    __syncthreads();

    float4 acc = make_float4(0.f, 0.f, 0.f, 0.f);
    for (int i = 0; i < Hn; i += 4) {
      float xs[4], ps[4];
      *(float4*)xs = *(const float4*)&cs[erow][i];
      *(float4*)ps = *(const float4*)&ph[erow][i];
#pragma unroll
      for (int k = 0; k < 4; k++) {
        float4 wc4 = *(const float4*)(wcp + (size_t)(i + k) * Hn);
        float4 wr4 = *(const float4*)(wrp + (size_t)(i + k) * Hn);
        acc.x += xs[k] * wc4.x + ps[k] * wr4.x;
        acc.y += xs[k] * wc4.y + ps[k] * wr4.y;
        acc.z += xs[k] * wc4.z + ps[k] * wr4.z;
        acc.w += xs[k] * wc4.w + ps[k] * wr4.w;
      }
    }
    if (erow < ne) {
      int e = eidx[erow];
      float4 bcv = *(const float4*)(bc + m * Hn + col);
      float4 brv = *(const float4*)(br + m * Hn + col);
      int tok = inp[e];  // [B,1] int32 (always 0 for the 1-row table)
      float4 lv = *(const float4*)(lut + (size_t)tok * Hn + col);
      float4 ev = *(const float4*)(enc_bias + col);
      float4 o;
      o.x = tanhf(acc.x + bcv.x + brv.x + lv.x + ev.x);
      o.y = tanhf(acc.y + bcv.y + brv.y + lv.y + ev.y);
      o.z = tanhf(acc.z + bcv.z + brv.z + lv.z + ev.z);
      o.w = tanhf(acc.w + bcv.w + brv.w + lv.w + ev.w);
      *(float4*)(hid_out + e * Hn + col) = o;
    }
    __syncthreads();
  }
}

// ---------------- kernel 3: comm_out = (hid @ Wo + bo) / (NAG-1) ----------------
// E=32 examples/block so Wo (64MB) is streamed ~exactly once.
// block = 256 threads = 16 eg-groups (2 ex each) x 16 col4-groups (64 cols).
// grid = (32 models, 32 col-tiles, 2 chunks) = 1024 active blocks (4/CU).
__global__ __launch_bounds__(256) void k_out(
    const float* __restrict__ hid, const float* __restrict__ Wo,
    const float* __restrict__ bo, const int* __restrict__ ofs,
    const int* __restrict__ list, float* __restrict__ comm_out) {
  constexpr int E = 32;
  int m = blockIdx.x;
  int ct = blockIdx.y;
  int ch = blockIdx.z;
  int beg = ofs[m], end = ofs[m + 1];
  if (beg + ch * E >= end) return;

  __shared__ float hs[E][HP];   // 33.3KB
  __shared__ int eidx[E];

  int tid = threadIdx.x;
  int col4 = tid & 15;
  int eg = tid >> 4;
  int col = ct * 64 + col4 * 4;
  const float* wp = Wo + (size_t)m * Hn * On + col;

  for (int base0 = beg + ch * E; base0 < end; base0 += 2 * E) {
    int ne = min(E, end - base0);
    if (tid < E) eidx[tid] = list[base0 + min(tid, ne - 1)];
    __syncthreads();
#pragma unroll
    for (int j = 0; j < E; j++) hs[j][tid] = hid[eidx[j] * Hn + tid];
    __syncthreads();

    int j0 = eg * 2, j1 = j0 + 1;
    float4 a0 = make_float4(0.f, 0.f, 0.f, 0.f);
    float4 a1 = make_float4(0.f, 0.f, 0.f, 0.f);
    for (int i = 0; i < Hn; i += 4) {
      float x0[4], x1[4];
      *(float4*)x0 = *(const float4*)&hs[j0][i];
      *(float4*)x1 = *(const float4*)&hs[j1][i];
#pragma unroll
      for (int k = 0; k < 4; k++) {
        float4 w4 = *(const float4*)(wp + (size_t)(i + k) * On);
        a0.x += x0[k] * w4.x; a0.y += x0[k] * w4.y;
        a0.z += x0[k] * w4.z; a0.w += x0[k] * w4.w;
        a1.x += x1[k] * w4.x; a1.y += x1[k] * w4.y;
        a1.z += x1[k] * w4.z; a1.w += x1[k] * w4.w;
      }
    }
    float4 bv = *(const float4*)(bo + (size_t)m * On + col);
    constexpr float inv = 1.0f / (NAGn - 1);
    if (j0 < ne) {
      int e = eidx[j0];
      float4 o;
      o.x = (a0.x + bv.x) * inv; o.y = (a0.y + bv.y) * inv;
      o.z = (a0.z + bv.z) * inv; o.w = (a0.w + bv.w) * inv;
      *(float4*)(comm_out + (size_t)e * On + col) = o;
    }
    if (j1 < ne) {
      int e = eidx[j1];
      float4 o;
      o.x = (a1.x + bv.x) * inv; o.y = (a1.y + bv.y) * inv;
      o.z = (a1.z + bv.z) * inv; o.w = (a1.w + bv.w) * inv;
      *(float4*)(comm_out + (size_t)e * On + col) = o;
    }
    __syncthreads();
  }
}

// ---------------- kernel 4: action softmax + baseline, 1 wave / example -------
__global__ __launch_bounds__(64) void k_act(
    const float* __restrict__ hid, const float* __restrict__ Wa,
    const float* __restrict__ ba, const float* __restrict__ Wb,
    const float* __restrict__ bb, const int* __restrict__ ids,
    float* __restrict__ aprob, float* __restrict__ bl) {
  int b = blockIdx.x;
  int m = ids[b];
  int l = threadIdx.x;
  int o = l & 15;       // action index
  int part = l >> 4;    // 4-way split of the K=256 reduction

  const float* hp = hid + b * Hn + part * 64;
  const float* wap = Wa + ((size_t)m * Hn + part * 64) * NACTn + o;
  float al = 0.f;
  for (int i = 0; i < 64; i++) al += hp[i] * wap[i * NACTn];
  al += __shfl_xor(al, 16);
  al += __shfl_xor(al, 32);           // full dot in every lane
  al += ba[m * NACTn + o];

  float mx = al;
  mx = fmaxf(mx, __shfl_xor(mx, 1));
  mx = fmaxf(mx, __shfl_xor(mx, 2));
  mx = fmaxf(mx, __shfl_xor(mx, 4));
  mx = fmaxf(mx, __shfl_xor(mx, 8));
  float ex = expf(al - mx);
  float sm = ex;
  sm += __shfl_xor(sm, 1);
  sm += __shfl_xor(sm, 2);
  sm += __shfl_xor(sm, 4);
  sm += __shfl_xor(sm, 8);
  if (l < 16) aprob[b * NACTn + l] = ex / sm;

  // baseline (H -> 1)
  float pb = 0.f;
  const float* hb = hid + b * Hn;
  const float* wbp = Wb + (size_t)m * Hn;
#pragma unroll
  for (int k = 0; k < 4; k++) pb += hb[l + k * 64] * wbp[l + k * 64];
  pb += __shfl_xor(pb, 1);
  pb += __shfl_xor(pb, 2);
  pb += __shfl_xor(pb, 4);
  pb += __shfl_xor(pb, 8);
  pb += __shfl_xor(pb, 16);
  pb += __shfl_xor(pb, 32);
  if (l == 0) bl[b] = pb + bb[m];
}

extern "C" void kernel_launch(void* const* d_in, const int* in_sizes, int n_in,
                              void* d_out, int out_size, void* d_ws, size_t ws_size,
                              hipStream_t stream) {
  const float* comm_in  = (const float*)d_in[0];
  const int*   inp      = (const int*)d_in[1];
  const float* prev_hid = (const float*)d_in[2];
  // d_in[3] = prev_cell (unused in rnn branch)
  const int*   ids      = (const int*)d_in[4];
  const float* Wc = (const float*)d_in[5];
  const float* bc = (const float*)d_in[6];
  const float* Wr = (const float*)d_in[7];
  const float* br = (const float*)d_in[8];
  const float* Wa = (const float*)d_in[9];
  const float* ba = (const float*)d_in[10];
  const float* Wb = (const float*)d_in[11];
  const float* bb = (const float*)d_in[12];
  const float* Wo = (const float*)d_in[13];
  const float* bo = (const float*)d_in[14];
  const float* lut      = (const float*)d_in[15];
  const float* enc_bias = (const float*)d_in[16];

  float* out      = (float*)d_out;
  float* aprob    = out;                       // [512,16]
  float* bl       = out + Bn * NACTn;          // [512,1]   @ 8192
  float* hid      = out + Bn * NACTn + Bn;     // [512,256] @ 8704
  float* comm_out = hid + Bn * Hn;             // [512,2048]@ 139776

  int* ofs  = (int*)d_ws;      // 33 ints
  int* list = ofs + 64;        // 512 ints

  k_group<<<1, 512, 0, stream>>>(ids, ofs, list);
  k_hid<<<dim3(Mn, 4, 4), 256, 0, stream>>>(comm_in, inp, prev_hid, Wc, bc, Wr, br,
                                            lut, enc_bias, ofs, list, hid);
  k_out<<<dim3(Mn, 32, 2), 256, 0, stream>>>(hid, Wo, bo, ofs, list, comm_out);
  k_act<<<Bn, 64, 0, stream>>>(hid, Wa, ba, Wb, bb, ids, aprob, bl);
}